// Round 2
// baseline (1077.650 us; speedup 1.0000x reference)
//
#include <hip/hip_runtime.h>
#include <stdint.h>

#define B_ 128
#define K_ 16
#define V_ 50257
#define T_ 20
#define H_ 512
#define NPREV 256          // 16*K prev-decision tokens per batch
#define BM_WORDS 1600      // ceil(50257/32)=1571, padded
#define EOSP 1000.0f
#define LAMBDA 0.5f

// out layout (floats): [0]=new_beam_seq(40960) [1]=logprobs(40960) [2]=sel_p(2048) [3]=state(4194304)
#define OUT1 40960
#define OUT2 81920
#define OUT3 83968

typedef unsigned long long ull;

__device__ __forceinline__ unsigned key32_of(float f) {
  unsigned u = __float_as_uint(f);
  return (u & 0x80000000u) ? ~u : (u | 0x80000000u);
}
__device__ __forceinline__ float float_of_key32(unsigned k) {
  unsigned u = (k & 0x80000000u) ? (k ^ 0x80000000u) : ~k;
  return __uint_as_float(u);
}

// ---------------- kernel 0: per-batch penalty set (bitmap + deduped counts) ----
__global__ __launch_bounds__(256) void k0_pen(const int* __restrict__ prev,
    unsigned* __restrict__ bitmap, int* __restrict__ pen_tok,
    float* __restrict__ pen_val) {
  const int b = blockIdx.x, tid = threadIdx.x;
  __shared__ int toks[NPREV];
  for (int i = tid; i < BM_WORDS; i += 256) bitmap[b * BM_WORDS + i] = 0u;
  int tok = prev[b * NPREV + tid];
  toks[tid] = tok;
  __syncthreads();   // orders the zero-stores before the atomics (block-local)
  int cnt = 0; bool first = true;
  for (int j = 0; j < NPREV; ++j) {
    int tj = toks[j];
    cnt += (tj == tok) ? 1 : 0;
    if (j < tid && tj == tok) first = false;
  }
  pen_tok[b * NPREV + tid] = first ? tok : -1;
  pen_val[b * NPREV + tid] = LAMBDA * (float)cnt;
  atomicOr(&bitmap[b * BM_WORDS + (tok >> 5)], 1u << (tok & 31));
}

// ---------------- kernel 1: per-(b,k) exact top-16 of augmented logprobs ------
__global__ __launch_bounds__(256) void k1_topk(
    const float* __restrict__ lp, const unsigned* __restrict__ bitmap,
    const int* __restrict__ pen_tok, const float* __restrict__ pen_val,
    float* __restrict__ topv, int* __restrict__ topi) {
  const int row = blockIdx.x;          // b*K + k
  const int b = row >> 4;
  const int tid = threadIdx.x;
  const float* __restrict__ rp = lp + (size_t)row * V_;

  __shared__ unsigned bm[BM_WORDS];
  __shared__ ull pool[256 * 16 + NPREV];

  for (int i = tid; i < BM_WORDS; i += 256) bm[i] = bitmap[b * BM_WORDS + i];
  __syncthreads();

  ull L[16];
  #pragma unroll
  for (int i = 0; i < 16; ++i) L[i] = 0;
  ull gate = 0;

  auto proc = [&](float f, int idx) {
    if (idx == V_ - 1) f -= EOSP;
    ull key = ((ull)key32_of(f) << 32) | (unsigned)(~(unsigned)idx);
    if (key > gate && key > L[15]) {
      if (!((bm[idx >> 5] >> (idx & 31)) & 1u)) {   // skip penalized tokens
        L[15] = key;
        #pragma unroll
        for (int i = 15; i > 0; --i) {
          if (L[i] > L[i - 1]) { ull tmp = L[i]; L[i] = L[i - 1]; L[i - 1] = tmp; }
        }
      }
    }
  };

  // V%4==1 -> (row*V)%4 == row%4; align the float4 stream per row
  const int a = (4 - (row & 3)) & 3;
  const int nvec = (V_ - a) >> 2;
  const int ntail = V_ - a - (nvec << 2);
  if (tid < a) proc(rp[tid], tid);
  const float4* __restrict__ vp = reinterpret_cast<const float4*>(rp + a);
  const int niter = (nvec + 255) >> 8;
  for (int ii = 0; ii < niter; ++ii) {
    int it = (ii << 8) + tid;
    if (it < nvec) {
      float4 v = vp[it];
      int idx0 = a + (it << 2);
      proc(v.x, idx0); proc(v.y, idx0 + 1); proc(v.z, idx0 + 2); proc(v.w, idx0 + 3);
    }
    if ((ii & 7) == 7) {         // refresh shared gate: max over lane list-minima
      ull g = L[15];
      #pragma unroll
      for (int off = 32; off; off >>= 1) {
        ull o = __shfl_xor(g, off, 64);
        if (o > g) g = o;
      }
      if (g > gate) gate = g;
    }
  }
  if (tid < ntail) { int idx = a + (nvec << 2) + tid; proc(rp[idx], idx); }

  // dump lane lists + penalized candidates into LDS pool
  #pragma unroll
  for (int i = 0; i < 16; ++i) pool[tid * 16 + i] = L[i];
  {
    int tok = pen_tok[b * NPREV + tid];
    ull key = 0;
    if (tok >= 0) {
      float f = rp[tok];
      if (tok == V_ - 1) f -= EOSP;
      f -= pen_val[b * NPREV + tid];
      key = ((ull)key32_of(f) << 32) | (unsigned)(~(unsigned)tok);
    }
    pool[4096 + tid] = key;
  }
  __syncthreads();

  const int POOL = 4096 + NPREV;
  for (int m = 0; m < 16; ++m) {
    if (tid < 64) {
      ull bkey = 0; int bpos = 0;
      for (int i = tid; i < POOL; i += 64) {
        ull v = pool[i];
        if (v > bkey) { bkey = v; bpos = i; }
      }
      #pragma unroll
      for (int off = 32; off; off >>= 1) {
        ull ok = __shfl_xor(bkey, off, 64);
        int op = __shfl_xor(bpos, off, 64);
        if (ok > bkey) { bkey = ok; bpos = op; }
      }
      if (tid == 0) {
        pool[bpos] = 0;
        topi[row * 16 + m] = (int)(~(unsigned)bkey);
        topv[row * 16 + m] = float_of_key32((unsigned)(bkey >> 32));
      }
    }
    __syncthreads();
  }
}

// ---------------- kernel 2: per-batch global top-16 + beam-history writes -----
__global__ __launch_bounds__(256) void k2_select(
    const float* __restrict__ lp, const int* __restrict__ beam_seq,
    const float* __restrict__ beam_lps, const float* __restrict__ bls,
    const int* __restrict__ t_ptr, const float* __restrict__ topv,
    const int* __restrict__ topi, float* __restrict__ out,
    int* __restrict__ qsel) {
  const int b = blockIdx.x;
  const int tid = threadIdx.x;
  const int t = *t_ptr;
  __shared__ ull pool[256];
  __shared__ int s_q[16]; __shared__ int s_tok[16]; __shared__ float s_r[16];

  int k = tid >> 4, j = tid & 15;
  float cv = bls[b * 16 + k] + topv[(b * 16 + k) * 16 + j];
  pool[tid] = ((ull)key32_of(cv) << 32) | (unsigned)(~(unsigned)tid);
  __syncthreads();

  for (int m = 0; m < 16; ++m) {
    if (tid < 64) {
      ull bkey = 0; int bpos = 0;
      #pragma unroll
      for (int s = 0; s < 4; ++s) {
        int i = tid + (s << 6);
        ull v = pool[i];
        if (v > bkey) { bkey = v; bpos = i; }
      }
      #pragma unroll
      for (int off = 32; off; off >>= 1) {
        ull ok = __shfl_xor(bkey, off, 64);
        int op = __shfl_xor(bpos, off, 64);
        if (ok > bkey) { bkey = ok; bpos = op; }
      }
      if (tid == 0) {
        pool[bpos] = 0;
        int ctid = (int)(~(unsigned)bkey) & 255;
        int q = ctid >> 4, col = ctid & 15;
        int tok = topi[(b * 16 + q) * 16 + col];
        float val = float_of_key32((unsigned)(bkey >> 32));
        float r = lp[(size_t)(b * 16 + q) * V_ + tok];
        if (tok == V_ - 1) r -= EOSP;
        s_q[m] = q; s_tok[m] = tok; s_r[m] = r;
        qsel[b * 16 + m] = q;
        out[OUT2 + b * 16 + m] = val;
      }
    }
    __syncthreads();
  }

  for (int e = tid; e < T_ * 16; e += 256) {
    int i = e >> 4, m = e & 15;
    float o0, o1;
    if (i < t) {
      int q = s_q[m];
      o0 = (float)beam_seq[(b * T_ + i) * 16 + q];
      o1 = beam_lps[(b * T_ + i) * 16 + q];
    } else if (i == t) {
      o0 = (float)s_tok[m];
      o1 = s_r[m];
    } else {
      o0 = (float)beam_seq[(b * T_ + i) * 16 + m];
      o1 = beam_lps[(b * T_ + i) * 16 + m];
    }
    out[b * (T_ * 16) + e] = o0;
    out[OUT1 + b * (T_ * 16) + e] = o1;
  }
}

// ---------------- kernel 3: state gather along beam dim -----------------------
__global__ __launch_bounds__(256) void k3_state(
    const float* __restrict__ state, const int* __restrict__ qsel,
    float* __restrict__ out3) {
  int gid = blockIdx.x * 256 + threadIdx.x;   // over 2*2*128*16*128 float4
  int h4 = gid & 127;
  int rest = gid >> 7;
  int m = rest & 15; rest >>= 4;
  int b = rest & 127; rest >>= 7;             // rest = s*2+l in 0..3
  int q = qsel[b * 16 + m];
  const float4* src = reinterpret_cast<const float4*>(state) +
                      ((size_t)((rest * B_ + b) * 16 + q) * 128 + h4);
  float4* dst = reinterpret_cast<float4*>(out3) +
                ((size_t)((rest * B_ + b) * 16 + m) * 128 + h4);
  *dst = *src;
}

extern "C" void kernel_launch(void* const* d_in, const int* in_sizes, int n_in,
                              void* d_out, int out_size, void* d_ws, size_t ws_size,
                              hipStream_t stream) {
  const float* lp       = (const float*)d_in[0];
  const int*   beam_seq = (const int*)d_in[1];
  const float* beam_lps = (const float*)d_in[2];
  const float* bls      = (const float*)d_in[3];
  const float* state    = (const float*)d_in[4];
  const int*   prev     = (const int*)d_in[5];
  const int*   t_ptr    = (const int*)d_in[6];
  float* out = (float*)d_out;

  char* ws = (char*)d_ws;
  unsigned* bitmap = (unsigned*)ws;                 // 128*1600*4  = 819200
  int*   pen_tok = (int*)  (ws + 819200);           // 128*256*4   = 131072
  float* pen_val = (float*)(ws + 950272);           // 131072
  float* topv    = (float*)(ws + 1081344);          // 2048*16*4   = 131072
  int*   topi    = (int*)  (ws + 1212416);          // 131072
  int*   qsel    = (int*)  (ws + 1343488);          // 128*16*4    = 8192

  k0_pen  <<<B_, 256, 0, stream>>>(prev, bitmap, pen_tok, pen_val);
  k1_topk <<<B_ * K_, 256, 0, stream>>>(lp, bitmap, pen_tok, pen_val, topv, topi);
  k2_select<<<B_, 256, 0, stream>>>(lp, beam_seq, beam_lps, bls, t_ptr,
                                    topv, topi, out, qsel);
  k3_state<<<(2 * 2 * B_ * K_ * (H_ / 4)) / 256, 256, 0, stream>>>(state, qsel, out + OUT3);
}